// Round 1
// baseline (247.307 us; speedup 1.0000x reference)
//
#include <hip/hip_runtime.h>
#include <hip/hip_bf16.h>

typedef __attribute__((ext_vector_type(8))) short short8;
typedef __attribute__((ext_vector_type(4))) float f32x4;

__device__ __forceinline__ short f2bf(float x) {
    __hip_bfloat16 h = __float2bfloat16(x);
    return __builtin_bit_cast(short, h);
}

__device__ __forceinline__ void gload16(const void* g, void* l) {
    __builtin_amdgcn_global_load_lds(
        (const __attribute__((address_space(1))) void*)g,
        (__attribute__((address_space(3))) void*)l, 16, 0, 0);
}

// ---------------------------------------------------------------------------
// fp32 -> bf16 conversion. blockIdx.y selects among up to 4 source tensors;
// destinations are contiguous slabs of `per` elements in ws.
// ---------------------------------------------------------------------------
__global__ __launch_bounds__(256) void cvt_bf16_kernel(
    const float* __restrict__ s0, const float* __restrict__ s1,
    const float* __restrict__ s2, const float* __restrict__ s3,
    __hip_bfloat16* __restrict__ dbase, int per) {
    const float* s = (blockIdx.y == 0) ? s0 : (blockIdx.y == 1) ? s1
                   : (blockIdx.y == 2) ? s2 : s3;
    short* d = (short*)(dbase + (size_t)blockIdx.y * per);
    int i = (blockIdx.x * 256 + threadIdx.x) * 8;
    float4 a = *(const float4*)(s + i);
    float4 b = *(const float4*)(s + i + 4);
    short8 o;
    o[0] = f2bf(a.x); o[1] = f2bf(a.y); o[2] = f2bf(a.z); o[3] = f2bf(a.w);
    o[4] = f2bf(b.x); o[5] = f2bf(b.y); o[6] = f2bf(b.z); o[7] = f2bf(b.w);
    *(short8*)(d + i) = o;
}

// ---------------------------------------------------------------------------
// 128x128x(K=1024) GEMM core, C = A @ W^T.  A: [M][1024] bf16 row-major
// (pre-offset to this block's 128 rows), W: [N][1024] bf16 row-major
// (pre-offset to this block's 128 output cols). m97 structure: BK=32,
// global_load_lds width 16, 4 waves in 2x2, each wave 4x4 16x16 frags.
// ---------------------------------------------------------------------------
__device__ __forceinline__ void gemm128_core(const char* Ab, const char* Wb,
                                             short* Al, short* Bl,
                                             f32x4 (&acc)[4][4]) {
    const int tid = threadIdx.x, lane = tid & 63, wid = tid >> 6;
    const int lr = lane & 15, lg = lane >> 4;
    const int wr = wid >> 1, wc = wid & 1;
    for (int kt = 0; kt < 32; ++kt) {
#pragma unroll
        for (int i = 0; i < 2; ++i) {
            int slot0 = (wid * 2 + i) * 64;     // wave-uniform LDS chunk
            int slot = slot0 + lane;
            int row = slot >> 2;                // 4 lanes (64B) per row
            int cb = (slot & 3) << 4;           // byte offset in row
            size_t goff = (size_t)row * 2048 + (kt << 6) + cb;
            gload16(Ab + goff, (char*)Al + (slot0 << 4));
            gload16(Wb + goff, (char*)Bl + (slot0 << 4));
        }
        __syncthreads();   // drains vmcnt before barrier (compiler-inserted)
        short8 af[4], bw[4];
#pragma unroll
        for (int m = 0; m < 4; ++m)
            af[m] = *(const short8*)(Al + ((64 * wr + 16 * m + lr) << 5) + (lg << 3));
#pragma unroll
        for (int n = 0; n < 4; ++n)
            bw[n] = *(const short8*)(Bl + ((64 * wc + 16 * n + lr) << 5) + (lg << 3));
#pragma unroll
        for (int m = 0; m < 4; ++m)
#pragma unroll
            for (int n = 0; n < 4; ++n)
                acc[m][n] = __builtin_amdgcn_mfma_f32_16x16x32_bf16(
                    af[m], bw[n], acc[m][n], 0, 0, 0);
        __syncthreads();
    }
}

// ---------------------------------------------------------------------------
// Fused Q/K/V projection: z = blockIdx.z selects tensor. Output written
// bf16 in head-major layout [B,H,S,DK] (per-tensor slab of 4194304).
// ---------------------------------------------------------------------------
__global__ __launch_bounds__(256) void proj_gemm_kernel(
    const __hip_bfloat16* __restrict__ ins,   // [3][4096*1024]
    const __hip_bfloat16* __restrict__ wts,   // [3][1024*1024] (Wq,Wk,Wv)
    const float* __restrict__ b0, const float* __restrict__ b1,
    const float* __restrict__ b2,
    __hip_bfloat16* __restrict__ outs) {      // [3][B,H,S,DK]
    __shared__ __align__(16) short Al[128 * 32];
    __shared__ __align__(16) short Bl[128 * 32];
    const int z = blockIdx.z;
    const char* Ab = (const char*)(ins + (size_t)z * 4194304)
                     + (size_t)blockIdx.y * 128 * 2048;
    const char* Wb = (const char*)(wts + (size_t)z * 1048576)
                     + (size_t)blockIdx.x * 128 * 2048;
    const float* bias = (z == 0) ? b0 : (z == 1) ? b1 : b2;
    __hip_bfloat16* out = outs + (size_t)z * 4194304;

    f32x4 acc[4][4] = {};
    gemm128_core(Ab, Wb, Al, Bl, acc);

    const int tid = threadIdx.x, lane = tid & 63, wid = tid >> 6;
    const int lr = lane & 15, lg = lane >> 4;
    const int wr = wid >> 1, wc = wid & 1;
    int col0 = (blockIdx.x << 7) + (wc << 6);
    int row0 = (blockIdx.y << 7) + (wr << 6);
#pragma unroll
    for (int n = 0; n < 4; ++n) {
        int col = col0 + 16 * n + lr;       // e in [0,1024): h*64+dk
        float bb = bias[col];
        int hh = col >> 6, dk = col & 63;
#pragma unroll
        for (int m = 0; m < 4; ++m) {
#pragma unroll
            for (int r = 0; r < 4; ++r) {
                int row = row0 + 16 * m + 4 * lg + r;  // b*2048+s
                int bat = row >> 11, s = row & 2047;
                out[((size_t)((bat * 16 + hh) * 2048 + s) << 6) + dk] =
                    __float2bfloat16(acc[m][n][r] + bb);
            }
        }
    }
}

// ---------------------------------------------------------------------------
// Output projection: out = X @ Wo^T + bo, fp32 output.
// ---------------------------------------------------------------------------
__global__ __launch_bounds__(256) void out_gemm_kernel(
    const __hip_bfloat16* __restrict__ X, const __hip_bfloat16* __restrict__ Wo,
    const float* __restrict__ bias, float* __restrict__ out) {
    __shared__ __align__(16) short Al[128 * 32];
    __shared__ __align__(16) short Bl[128 * 32];
    const char* Ab = (const char*)X + (size_t)blockIdx.y * 128 * 2048;
    const char* Wb = (const char*)Wo + (size_t)blockIdx.x * 128 * 2048;
    f32x4 acc[4][4] = {};
    gemm128_core(Ab, Wb, Al, Bl, acc);

    const int tid = threadIdx.x, lane = tid & 63, wid = tid >> 6;
    const int lr = lane & 15, lg = lane >> 4;
    const int wr = wid >> 1, wc = wid & 1;
    int col0 = (blockIdx.x << 7) + (wc << 6);
    int row0 = (blockIdx.y << 7) + (wr << 6);
#pragma unroll
    for (int n = 0; n < 4; ++n) {
        int col = col0 + 16 * n + lr;
        float bb = bias[col];
#pragma unroll
        for (int m = 0; m < 4; ++m)
#pragma unroll
            for (int r = 0; r < 4; ++r) {
                int row = row0 + 16 * m + 4 * lg + r;
                out[((size_t)row << 10) + col] = acc[m][n][r] + bb;
            }
    }
}

// ---------------------------------------------------------------------------
// Flash attention, causal. Block = (qt, h, b): 64 q-rows, 4 waves x 16 rows.
// K staged [64][72] (stride-72 bf16 keeps 16B alignment, breaks the 16-way
// bank conflict of stride-64), V staged transposed [dk][kv] so the PV
// B-fragment is a contiguous ds_read_b128. Online softmax per wave; P goes
// through LDS as bf16 to become the PV A-operand.
// ---------------------------------------------------------------------------
__global__ __launch_bounds__(256) void attn_kernel(
    const __hip_bfloat16* __restrict__ qb, const __hip_bfloat16* __restrict__ kb,
    const __hip_bfloat16* __restrict__ vb, __hip_bfloat16* __restrict__ xb) {
    __shared__ __align__(16) short Ql[64 * 72];
    __shared__ __align__(16) short Kl[64 * 72];
    __shared__ __align__(16) short Vl[64 * 72];   // transposed: [dk][kv]
    __shared__ __align__(16) short Pl[4 * 16 * 72];
    const int tid = threadIdx.x, lane = tid & 63, wid = tid >> 6;
    const int lr = lane & 15, lg = lane >> 4;
    const int qt = blockIdx.x, h = blockIdx.y, b = blockIdx.z;
    const size_t hb = (size_t)(b * 16 + h) * (2048 * 64);
    const int q0 = qt << 6;

    {   // stage Q (contiguous 8 KB)
        const short* src = (const short*)qb + hb + (size_t)q0 * 64;
#pragma unroll
        for (int i = 0; i < 2; ++i) {
            int slot = i * 256 + tid;
            int row = slot >> 3, ce = (slot & 7) << 3;
            *(short8*)(Ql + row * 72 + ce) = *(const short8*)(src + row * 64 + ce);
        }
    }
    __syncthreads();
    short8 qa[2];
#pragma unroll
    for (int kk = 0; kk < 2; ++kk)
        qa[kk] = *(const short8*)(Ql + (16 * wid + lr) * 72 + kk * 32 + (lg << 3));

    f32x4 o[4] = {};
    float mrun[4], lrun[4];
#pragma unroll
    for (int r = 0; r < 4; ++r) { mrun[r] = -1e30f; lrun[r] = 0.f; }
    const int qrow0 = q0 + 16 * wid + 4 * lg;

    for (int t = 0; t <= qt; ++t) {
        __syncthreads();   // previous tile's LDS reads done
        {
            const short* ks = (const short*)kb + hb + (size_t)t * 4096;
            const short* vs = (const short*)vb + hb + (size_t)t * 4096;
#pragma unroll
            for (int i = 0; i < 2; ++i) {
                int slot = i * 256 + tid;
                int row = slot >> 3, ce = (slot & 7) << 3;
                *(short8*)(Kl + row * 72 + ce) = *(const short8*)(ks + row * 64 + ce);
                short8 vv = *(const short8*)(vs + row * 64 + ce);
#pragma unroll
                for (int j = 0; j < 8; ++j) Vl[(ce + j) * 72 + row] = vv[j];
            }
        }
        __syncthreads();

        // scores: S = Q K^T (per wave: 16 x 64)
        f32x4 sc[4] = {};
#pragma unroll
        for (int kk = 0; kk < 2; ++kk)
#pragma unroll
            for (int n = 0; n < 4; ++n) {
                short8 kf = *(const short8*)(Kl + (16 * n + lr) * 72 + kk * 32 + (lg << 3));
                sc[n] = __builtin_amdgcn_mfma_f32_16x16x32_bf16(qa[kk], kf, sc[n], 0, 0, 0);
            }

        const int kv0 = t << 6;
        float rmax[4] = {-1e30f, -1e30f, -1e30f, -1e30f};
#pragma unroll
        for (int n = 0; n < 4; ++n) {
            int kvg = kv0 + 16 * n + lr;
#pragma unroll
            for (int r = 0; r < 4; ++r) {
                float v = sc[n][r] * 0.125f;            // 1/sqrt(64)
                if (kvg > qrow0 + r) v = -1e30f;        // causal
                sc[n][r] = v;
                rmax[r] = fmaxf(rmax[r], v);
            }
        }
#pragma unroll
        for (int d = 1; d < 16; d <<= 1)
#pragma unroll
            for (int r = 0; r < 4; ++r)
                rmax[r] = fmaxf(rmax[r], __shfl_xor(rmax[r], d));

        float psum[4];
#pragma unroll
        for (int r = 0; r < 4; ++r) {
            float mnew = fmaxf(mrun[r], rmax[r]);
            float corr = __expf(mrun[r] - mnew);
            mrun[r] = mnew;
            lrun[r] *= corr;
#pragma unroll
            for (int n = 0; n < 4; ++n) o[n][r] *= corr;
            psum[r] = 0.f;
        }
        short* pw = Pl + wid * (16 * 72);
#pragma unroll
        for (int n = 0; n < 4; ++n)
#pragma unroll
            for (int r = 0; r < 4; ++r) {
                float p = __expf(sc[n][r] - mrun[r]);
                psum[r] += p;
                pw[(4 * lg + r) * 72 + 16 * n + lr] = f2bf(p);
            }
#pragma unroll
        for (int d = 1; d < 16; d <<= 1)
#pragma unroll
            for (int r = 0; r < 4; ++r) psum[r] += __shfl_xor(psum[r], d);
#pragma unroll
        for (int r = 0; r < 4; ++r) lrun[r] += psum[r];
        __syncthreads();   // P visible (and ordered) before PV reads

        // PV: O += P @ V
#pragma unroll
        for (int kk = 0; kk < 2; ++kk) {
            short8 pa = *(const short8*)(pw + lr * 72 + kk * 32 + (lg << 3));
#pragma unroll
            for (int nd = 0; nd < 4; ++nd) {
                short8 vf = *(const short8*)(Vl + (16 * nd + lr) * 72 + kk * 32 + (lg << 3));
                o[nd] = __builtin_amdgcn_mfma_f32_16x16x32_bf16(pa, vf, o[nd], 0, 0, 0);
            }
        }
    }

    // epilogue: x[b][s][h*64+dk] = O / l, bf16
#pragma unroll
    for (int r = 0; r < 4; ++r) {
        float inv = 1.0f / lrun[r];
        int s = q0 + 16 * wid + 4 * lg + r;
        size_t rowoff = ((size_t)(b * 2048 + s) << 10) + (h << 6);
#pragma unroll
        for (int nd = 0; nd < 4; ++nd)
            xb[rowoff + 16 * nd + lr] = __float2bfloat16(o[nd][r] * inv);
    }
}

// ---------------------------------------------------------------------------
// Workspace layout (bf16 elems):
//   [0,         12582912)  converted query/key/value   (3 x 4194304)
//   [12582912,  16777216)  converted Wq,Wk,Wv,Wo       (4 x 1048576)
//   [16777216,  29360128)  projected Q,K,V head-major  (3 x 4194304)
//   x-buffer aliases [0, 4194304) (inputs dead after projections)
// total 58,720,256 bytes.
// ---------------------------------------------------------------------------
extern "C" void kernel_launch(void* const* d_in, const int* in_sizes, int n_in,
                              void* d_out, int out_size, void* d_ws, size_t ws_size,
                              hipStream_t stream) {
    const float* query = (const float*)d_in[0];
    const float* key_  = (const float*)d_in[1];
    const float* value = (const float*)d_in[2];
    // d_in[3] = mask: causal tril by construction, handled analytically
    const float* Wq = (const float*)d_in[4];
    const float* bq = (const float*)d_in[5];
    const float* Wk = (const float*)d_in[6];
    const float* bk = (const float*)d_in[7];
    const float* Wv = (const float*)d_in[8];
    const float* bv = (const float*)d_in[9];
    const float* Wo = (const float*)d_in[10];
    const float* bo = (const float*)d_in[11];

    __hip_bfloat16* ws    = (__hip_bfloat16*)d_ws;
    __hip_bfloat16* in_b  = ws;                 // 3 x 4194304
    __hip_bfloat16* w_b   = ws + 12582912;      // 4 x 1048576
    __hip_bfloat16* qkv_b = ws + 16777216;      // 3 x 4194304
    __hip_bfloat16* x_b   = ws;                 // alias converted inputs

    cvt_bf16_kernel<<<dim3(2048, 3), 256, 0, stream>>>(query, key_, value, query,
                                                       in_b, 4194304);
    cvt_bf16_kernel<<<dim3(512, 4), 256, 0, stream>>>(Wq, Wk, Wv, Wo,
                                                      w_b, 1048576);
    proj_gemm_kernel<<<dim3(8, 32, 3), 256, 0, stream>>>(in_b, w_b, bq, bk, bv,
                                                         qkv_b);
    attn_kernel<<<dim3(32, 16, 2), 256, 0, stream>>>(qkv_b, qkv_b + 4194304,
                                                     qkv_b + 8388608, x_b);
    out_gemm_kernel<<<dim3(8, 32), 256, 0, stream>>>(x_b, w_b + 3145728, bo,
                                                     (float*)d_out);
}

// Round 2
// 167.767 us; speedup vs baseline: 1.4741x; 1.4741x over previous
//
#include <hip/hip_runtime.h>
#include <hip/hip_bf16.h>

typedef __attribute__((ext_vector_type(8))) short short8;
typedef __attribute__((ext_vector_type(4))) short short4v;
typedef __attribute__((ext_vector_type(4))) float f32x4;

__device__ __forceinline__ short f2bf(float x) {
    __hip_bfloat16 h = __float2bfloat16(x);
    return __builtin_bit_cast(short, h);
}

__device__ __forceinline__ void gload16(const void* g, void* l) {
    __builtin_amdgcn_global_load_lds(
        (const __attribute__((address_space(1))) void*)g,
        (__attribute__((address_space(3))) void*)l, 16, 0, 0);
}

// ---------------------------------------------------------------------------
// fp32 -> bf16 conversion. blockIdx.y selects among up to 4 source tensors.
// ---------------------------------------------------------------------------
__global__ __launch_bounds__(256) void cvt_bf16_kernel(
    const float* __restrict__ s0, const float* __restrict__ s1,
    const float* __restrict__ s2, const float* __restrict__ s3,
    __hip_bfloat16* __restrict__ dbase, int per) {
    const float* s = (blockIdx.y == 0) ? s0 : (blockIdx.y == 1) ? s1
                   : (blockIdx.y == 2) ? s2 : s3;
    short* d = (short*)(dbase + (size_t)blockIdx.y * per);
    int i = (blockIdx.x * 256 + threadIdx.x) * 8;
    float4 a = *(const float4*)(s + i);
    float4 b = *(const float4*)(s + i + 4);
    short8 o;
    o[0] = f2bf(a.x); o[1] = f2bf(a.y); o[2] = f2bf(a.z); o[3] = f2bf(a.w);
    o[4] = f2bf(b.x); o[5] = f2bf(b.y); o[6] = f2bf(b.z); o[7] = f2bf(b.w);
    *(short8*)(d + i) = o;
}

// ---------------------------------------------------------------------------
// 128x128x(K=1024) GEMM core, C = A @ W^T (m97 structure).
// ---------------------------------------------------------------------------
__device__ __forceinline__ void gemm128_core(const char* Ab, const char* Wb,
                                             short* Al, short* Bl,
                                             f32x4 (&acc)[4][4]) {
    const int tid = threadIdx.x, lane = tid & 63, wid = tid >> 6;
    const int lr = lane & 15, lg = lane >> 4;
    const int wr = wid >> 1, wc = wid & 1;
    for (int kt = 0; kt < 32; ++kt) {
#pragma unroll
        for (int i = 0; i < 2; ++i) {
            int slot0 = (wid * 2 + i) * 64;     // wave-uniform LDS chunk
            int slot = slot0 + lane;
            int row = slot >> 2;                // 4 lanes (64B) per row
            int cb = (slot & 3) << 4;           // byte offset in row
            size_t goff = (size_t)row * 2048 + (kt << 6) + cb;
            gload16(Ab + goff, (char*)Al + (slot0 << 4));
            gload16(Wb + goff, (char*)Bl + (slot0 << 4));
        }
        __syncthreads();
        short8 af[4], bw[4];
#pragma unroll
        for (int m = 0; m < 4; ++m)
            af[m] = *(const short8*)(Al + ((64 * wr + 16 * m + lr) << 5) + (lg << 3));
#pragma unroll
        for (int n = 0; n < 4; ++n)
            bw[n] = *(const short8*)(Bl + ((64 * wc + 16 * n + lr) << 5) + (lg << 3));
#pragma unroll
        for (int m = 0; m < 4; ++m)
#pragma unroll
            for (int n = 0; n < 4; ++n)
                acc[m][n] = __builtin_amdgcn_mfma_f32_16x16x32_bf16(
                    af[m], bw[n], acc[m][n], 0, 0, 0);
        __syncthreads();
    }
}

// ---------------------------------------------------------------------------
// Q/K/V projection. z=0: Q head-major [B,H,S,DK]. z=1: K head-major,
// PRE-SCALED by 1/sqrt(DK)=0.125 (exact in bf16). z=2: V TRANSPOSED
// [B,H,DK,S] so attention's PV B-operand is a row-major read.
// ---------------------------------------------------------------------------
__global__ __launch_bounds__(256) void proj_gemm_kernel(
    const __hip_bfloat16* __restrict__ ins,   // [3][4096*1024]
    const __hip_bfloat16* __restrict__ wts,   // [3][1024*1024]
    const float* __restrict__ b0, const float* __restrict__ b1,
    const float* __restrict__ b2,
    __hip_bfloat16* __restrict__ outs) {
    __shared__ __align__(16) short Al[128 * 32];
    __shared__ __align__(16) short Bl[128 * 32];
    const int z = blockIdx.z;
    const char* Ab = (const char*)(ins + (size_t)z * 4194304)
                     + (size_t)blockIdx.y * 128 * 2048;
    const char* Wb = (const char*)(wts + (size_t)z * 1048576)
                     + (size_t)blockIdx.x * 128 * 2048;
    const float* bias = (z == 0) ? b0 : (z == 1) ? b1 : b2;
    __hip_bfloat16* out = outs + (size_t)z * 4194304;

    f32x4 acc[4][4] = {};
    gemm128_core(Ab, Wb, Al, Bl, acc);

    const int tid = threadIdx.x, lane = tid & 63, wid = tid >> 6;
    const int lr = lane & 15, lg = lane >> 4;
    const int wr = wid >> 1, wc = wid & 1;
    int col0 = (blockIdx.x << 7) + (wc << 6);
    int row0 = (blockIdx.y << 7) + (wr << 6);
    const float scale = (z == 1) ? 0.125f : 1.0f;
#pragma unroll
    for (int n = 0; n < 4; ++n) {
        int col = col0 + 16 * n + lr;       // e in [0,1024): h*64+dk
        float bb = bias[col];
        int hh = col >> 6, dk = col & 63;
        if (z == 2) {
#pragma unroll
            for (int m = 0; m < 4; ++m) {
                int row = row0 + 16 * m + 4 * lg;      // b*2048+s (4-aligned)
                int bat = row >> 11, s = row & 2047;
                short4v vv;
#pragma unroll
                for (int r = 0; r < 4; ++r) vv[r] = f2bf(acc[m][n][r] + bb);
                *(short4v*)((short*)out +
                    ((size_t)((bat * 16 + hh) * 64 + dk) << 11) + s) = vv;
            }
        } else {
#pragma unroll
            for (int m = 0; m < 4; ++m)
#pragma unroll
                for (int r = 0; r < 4; ++r) {
                    int row = row0 + 16 * m + 4 * lg + r;
                    int bat = row >> 11, s = row & 2047;
                    out[((size_t)((bat * 16 + hh) * 2048 + s) << 6) + dk] =
                        __float2bfloat16((acc[m][n][r] + bb) * scale);
                }
        }
    }
}

// ---------------------------------------------------------------------------
// Output projection: out = X @ Wo^T + bo, fp32 output.
// ---------------------------------------------------------------------------
__global__ __launch_bounds__(256) void out_gemm_kernel(
    const __hip_bfloat16* __restrict__ X, const __hip_bfloat16* __restrict__ Wo,
    const float* __restrict__ bias, float* __restrict__ out) {
    __shared__ __align__(16) short Al[128 * 32];
    __shared__ __align__(16) short Bl[128 * 32];
    const char* Ab = (const char*)X + (size_t)blockIdx.y * 128 * 2048;
    const char* Wb = (const char*)Wo + (size_t)blockIdx.x * 128 * 2048;
    f32x4 acc[4][4] = {};
    gemm128_core(Ab, Wb, Al, Bl, acc);

    const int tid = threadIdx.x, lane = tid & 63, wid = tid >> 6;
    const int lr = lane & 15, lg = lane >> 4;
    const int wr = wid >> 1, wc = wid & 1;
    int col0 = (blockIdx.x << 7) + (wc << 6);
    int row0 = (blockIdx.y << 7) + (wr << 6);
#pragma unroll
    for (int n = 0; n < 4; ++n) {
        int col = col0 + 16 * n + lr;
        float bb = bias[col];
#pragma unroll
        for (int m = 0; m < 4; ++m)
#pragma unroll
            for (int r = 0; r < 4; ++r) {
                int row = row0 + 16 * m + 4 * lg + r;
                out[((size_t)row << 10) + col] = acc[m][n][r] + bb;
            }
    }
}

// ---------------------------------------------------------------------------
// Flash attention v2, causal.
//  - Block = (pair, h, b): processes q-tiles {x, 31-x} sequentially ->
//    exactly 33 KV tiles/block (perfect balance). 4 waves x 16 q-rows.
//  - K (pre-scaled) and V^T staged via global_load_lds into linear [64][64]
//    LDS with XOR-16B-granule swizzle applied on the GLOBAL source address;
//    ds_read_b128 reads apply the same XOR -> conflict-free.
//  - Double-buffered: next tile's loads issued before current tile's
//    compute; raw s_barrier + manual counted s_waitcnt vmcnt(4) (never 0
//    mid-loop) keep the prefetch in flight across barriers.
//  - P round-trips through a per-wave XOR-swizzled [16][64] LDS tile.
// ---------------------------------------------------------------------------
#define SWZB(row, cb) ((cb) ^ (((row) & 7) << 4))

__device__ __forceinline__ void stage_kv(const short* kg, const short* vtg,
                                         short* Kbuf, short* Vbuf, int kv0,
                                         int wid, int lane) {
#pragma unroll
    for (int i = 0; i < 2; ++i) {
        int slot0 = (wid * 2 + i) * 64;
        int slot = slot0 + lane;
        int row = slot >> 3;          // K: kv row / V: dk row
        int cb = (slot & 7) << 4;     // 16B chunk within 128B row
        const char* gk = (const char*)(kg + (size_t)(kv0 + row) * 64)
                         + SWZB(row, cb);
        gload16(gk, (char*)Kbuf + (slot0 << 4));
        const char* gv = (const char*)(vtg + (size_t)row * 2048 + kv0)
                         + SWZB(row, cb);
        gload16(gv, (char*)Vbuf + (slot0 << 4));
    }
}

__global__ __launch_bounds__(256) void attn_kernel(
    const __hip_bfloat16* __restrict__ qb, const __hip_bfloat16* __restrict__ kb,
    const __hip_bfloat16* __restrict__ vtb, __hip_bfloat16* __restrict__ xb) {
    __shared__ __align__(16) short Kl[2][64 * 64];
    __shared__ __align__(16) short Vl[2][64 * 64];   // V^T: [dk][kv]
    __shared__ __align__(16) short Pl[4][16 * 64];
    const int tid = threadIdx.x, lane = tid & 63, wid = tid >> 6;
    const int lr = lane & 15, lg = lane >> 4;
    const int h = blockIdx.y, b = blockIdx.z;
    const size_t hb = (size_t)(b * 16 + h) * (2048 * 64);
    const short* qg = (const short*)qb + hb;
    const short* kg = (const short*)kb + hb;
    const short* vtg = (const short*)vtb + hb;   // [64][2048]
    char* pw = (char*)Pl[wid];

#pragma unroll 1
    for (int half = 0; half < 2; ++half) {
        const int qt = half ? (31 - (int)blockIdx.x) : (int)blockIdx.x;
        const int q0 = qt << 6;
        const int ntiles = qt + 1;

        // Q fragments straight to registers (row selector = lr)
        short8 qa[2];
        const char* qrow = (const char*)(qg + (size_t)q0 * 64)
                           + (16 * wid + lr) * 128 + (lg << 4);
        qa[0] = *(const short8*)(qrow);
        qa[1] = *(const short8*)(qrow + 64);

        f32x4 o[4] = {};
        float mrun[4], lrun[4];
#pragma unroll
        for (int r = 0; r < 4; ++r) { mrun[r] = -1e30f; lrun[r] = 0.f; }
        const int qrow0 = q0 + 16 * wid + 4 * lg;

        stage_kv(kg, vtg, Kl[0], Vl[0], 0, wid, lane);   // prologue
        int cur = 0;
#pragma unroll 1
        for (int t = 0; t < ntiles; ++t) {
            if (t + 1 < ntiles) {
                stage_kv(kg, vtg, Kl[cur ^ 1], Vl[cur ^ 1], (t + 1) << 6,
                         wid, lane);
                asm volatile("s_waitcnt vmcnt(4)" ::: "memory");
            } else {
                asm volatile("s_waitcnt vmcnt(0)" ::: "memory");
            }
            __builtin_amdgcn_s_barrier();   // all waves' slices staged

            const char* Kc = (const char*)Kl[cur];
            const char* Vc = (const char*)Vl[cur];

            // S = Q K^T  (16 q-rows x 64 kv)
            f32x4 sc[4] = {};
#pragma unroll
            for (int kk = 0; kk < 2; ++kk)
#pragma unroll
                for (int n = 0; n < 4; ++n) {
                    int row = 16 * n + lr;
                    short8 kf = *(const short8*)(Kc + row * 128 +
                                    SWZB(row, kk * 64 + (lg << 4)));
                    sc[n] = __builtin_amdgcn_mfma_f32_16x16x32_bf16(
                        qa[kk], kf, sc[n], 0, 0, 0);
                }

            // online softmax (K pre-scaled by 0.125)
            const int kv0 = t << 6;
            float rmax[4] = {-1e30f, -1e30f, -1e30f, -1e30f};
#pragma unroll
            for (int n = 0; n < 4; ++n) {
                int kvg = kv0 + 16 * n + lr;
#pragma unroll
                for (int r = 0; r < 4; ++r) {
                    float v = sc[n][r];
                    if (kvg > qrow0 + r) v = -1e30f;    // causal
                    sc[n][r] = v;
                    rmax[r] = fmaxf(rmax[r], v);
                }
            }
#pragma unroll
            for (int d = 1; d < 16; d <<= 1)
#pragma unroll
                for (int r = 0; r < 4; ++r)
                    rmax[r] = fmaxf(rmax[r], __shfl_xor(rmax[r], d));

            float psum[4];
#pragma unroll
            for (int r = 0; r < 4; ++r) {
                float mnew = fmaxf(mrun[r], rmax[r]);
                float corr = __expf(mrun[r] - mnew);
                mrun[r] = mnew;
                lrun[r] *= corr;
#pragma unroll
                for (int n = 0; n < 4; ++n) o[n][r] *= corr;
                psum[r] = 0.f;
            }
            // P -> per-wave swizzled LDS tile [16][64]
#pragma unroll
            for (int n = 0; n < 4; ++n)
#pragma unroll
                for (int r = 0; r < 4; ++r) {
                    float p = __expf(sc[n][r] - mrun[r]);
                    psum[r] += p;
                    int prow = 4 * lg + r;
                    *(short*)(pw + prow * 128 +
                              SWZB(prow, 32 * n + 2 * lr)) = f2bf(p);
                }
#pragma unroll
            for (int d = 1; d < 16; d <<= 1)
#pragma unroll
                for (int r = 0; r < 4; ++r) psum[r] += __shfl_xor(psum[r], d);
#pragma unroll
            for (int r = 0; r < 4; ++r) lrun[r] += psum[r];

            // O += P @ V   (B-operand = rows of V^T)
#pragma unroll
            for (int kk = 0; kk < 2; ++kk) {
                short8 pa = *(const short8*)(pw + lr * 128 +
                                SWZB(lr, kk * 64 + (lg << 4)));
#pragma unroll
                for (int nd = 0; nd < 4; ++nd) {
                    int row = 16 * nd + lr;
                    short8 vf = *(const short8*)(Vc + row * 128 +
                                    SWZB(row, kk * 64 + (lg << 4)));
                    o[nd] = __builtin_amdgcn_mfma_f32_16x16x32_bf16(
                        pa, vf, o[nd], 0, 0, 0);
                }
            }
            __builtin_amdgcn_s_barrier();   // all reads of buf `cur` done
            cur ^= 1;
        }

        // epilogue: x[b][s][h*64+dk] = O / l (bf16)
#pragma unroll
        for (int r = 0; r < 4; ++r) {
            float inv = 1.0f / lrun[r];
            int s = qrow0 + r;
            size_t rowoff = ((size_t)(b * 2048 + s) << 10) + (h << 6);
#pragma unroll
            for (int nd = 0; nd < 4; ++nd)
                xb[rowoff + 16 * nd + lr] = __float2bfloat16(o[nd][r] * inv);
        }
    }
}

// ---------------------------------------------------------------------------
// Workspace layout (bf16 elems):
//   [0,         12582912)  converted query/key/value   (3 x 4194304)
//   [12582912,  16777216)  converted Wq,Wk,Wv,Wo       (4 x 1048576)
//   [16777216,  29360128)  Q,K(scaled) head-major; V^T [B,H,DK,S]
//   x-buffer aliases [0, 4194304).
// ---------------------------------------------------------------------------
extern "C" void kernel_launch(void* const* d_in, const int* in_sizes, int n_in,
                              void* d_out, int out_size, void* d_ws, size_t ws_size,
                              hipStream_t stream) {
    const float* query = (const float*)d_in[0];
    const float* key_  = (const float*)d_in[1];
    const float* value = (const float*)d_in[2];
    // d_in[3] = mask: causal tril by construction, handled analytically
    const float* Wq = (const float*)d_in[4];
    const float* bq = (const float*)d_in[5];
    const float* Wk = (const float*)d_in[6];
    const float* bk = (const float*)d_in[7];
    const float* Wv = (const float*)d_in[8];
    const float* bv = (const float*)d_in[9];
    const float* Wo = (const float*)d_in[10];
    const float* bo = (const float*)d_in[11];

    __hip_bfloat16* ws    = (__hip_bfloat16*)d_ws;
    __hip_bfloat16* in_b  = ws;                 // 3 x 4194304
    __hip_bfloat16* w_b   = ws + 12582912;      // 4 x 1048576
    __hip_bfloat16* qkv_b = ws + 16777216;      // 3 x 4194304
    __hip_bfloat16* x_b   = ws;                 // alias converted inputs

    cvt_bf16_kernel<<<dim3(2048, 3), 256, 0, stream>>>(query, key_, value, query,
                                                       in_b, 4194304);
    cvt_bf16_kernel<<<dim3(512, 4), 256, 0, stream>>>(Wq, Wk, Wv, Wo,
                                                      w_b, 1048576);
    proj_gemm_kernel<<<dim3(8, 32, 3), 256, 0, stream>>>(in_b, w_b, bq, bk, bv,
                                                         qkv_b);
    attn_kernel<<<dim3(16, 16, 2), 256, 0, stream>>>(qkv_b, qkv_b + 4194304,
                                                     qkv_b + 8388608, x_b);
    out_gemm_kernel<<<dim3(8, 32), 256, 0, stream>>>(x_b, w_b + 3145728, bo,
                                                     (float*)d_out);
}

// Round 3
// 152.524 us; speedup vs baseline: 1.6214x; 1.0999x over previous
//
#include <hip/hip_runtime.h>
#include <hip/hip_bf16.h>

typedef __attribute__((ext_vector_type(8))) short short8;
typedef __attribute__((ext_vector_type(4))) short short4v;
typedef __attribute__((ext_vector_type(4))) float f32x4;

__device__ __forceinline__ short f2bf(float x) {
    __hip_bfloat16 h = __float2bfloat16(x);
    return __builtin_bit_cast(short, h);
}

__device__ __forceinline__ float exp2v(float x) {   // raw v_exp_f32 (exp2)
    float r;
    asm("v_exp_f32 %0, %1" : "=v"(r) : "v"(x));
    return r;
}

template <int CTRL>
__device__ __forceinline__ float fmax_ror(float x) { // DPP row_ror reduce step
    int xi = __builtin_bit_cast(int, x);
    int yi = __builtin_amdgcn_update_dpp(xi, xi, CTRL, 0xf, 0xf, false);
    return fmaxf(x, __builtin_bit_cast(float, yi));
}

__device__ __forceinline__ void gload16(const void* g, void* l) {
    __builtin_amdgcn_global_load_lds(
        (const __attribute__((address_space(1))) void*)g,
        (__attribute__((address_space(3))) void*)l, 16, 0, 0);
}

// ---------------------------------------------------------------------------
// fp32 -> bf16: all 7 tensors in one launch. dst layout = [q,k,v | Wq,Wk,Wv,Wo]
// ---------------------------------------------------------------------------
__global__ __launch_bounds__(256) void cvt_all_kernel(
    const float* __restrict__ q, const float* __restrict__ k,
    const float* __restrict__ v, const float* __restrict__ wq,
    const float* __restrict__ wk, const float* __restrict__ wv,
    const float* __restrict__ wo, short* __restrict__ dst) {
    size_t i = ((size_t)blockIdx.x * 256 + threadIdx.x) * 8;
    const float* s; size_t si;
    if (i < 12582912) {               // 3 x 2^22 input tensors
        int w = (int)(i >> 22);
        s = (w == 0) ? q : (w == 1) ? k : v;
        si = i & 4194303;
    } else {                          // 4 x 2^20 weights
        size_t j = i - 12582912;
        int w = (int)(j >> 20);
        s = (w == 0) ? wq : (w == 1) ? wk : (w == 2) ? wv : wo;
        si = j & 1048575;
    }
    float4 a = *(const float4*)(s + si);
    float4 b = *(const float4*)(s + si + 4);
    short8 o;
    o[0] = f2bf(a.x); o[1] = f2bf(a.y); o[2] = f2bf(a.z); o[3] = f2bf(a.w);
    o[4] = f2bf(b.x); o[5] = f2bf(b.y); o[6] = f2bf(b.z); o[7] = f2bf(b.w);
    *(short8*)(dst + i) = o;
}

// ---------------------------------------------------------------------------
// 128x128x(K=1024) GEMM core, C = A @ W^T (m97 structure).
// ---------------------------------------------------------------------------
__device__ __forceinline__ void gemm128_core(const char* Ab, const char* Wb,
                                             short* Al, short* Bl,
                                             f32x4 (&acc)[4][4]) {
    const int tid = threadIdx.x, lane = tid & 63, wid = tid >> 6;
    const int lr = lane & 15, lg = lane >> 4;
    const int wr = wid >> 1, wc = wid & 1;
    for (int kt = 0; kt < 32; ++kt) {
#pragma unroll
        for (int i = 0; i < 2; ++i) {
            int slot0 = (wid * 2 + i) * 64;     // wave-uniform LDS chunk
            int slot = slot0 + lane;
            int row = slot >> 2;                // 4 lanes (64B) per row
            int cb = (slot & 3) << 4;           // byte offset in row
            size_t goff = (size_t)row * 2048 + (kt << 6) + cb;
            gload16(Ab + goff, (char*)Al + (slot0 << 4));
            gload16(Wb + goff, (char*)Bl + (slot0 << 4));
        }
        __syncthreads();
        short8 af[4], bw[4];
#pragma unroll
        for (int m = 0; m < 4; ++m)
            af[m] = *(const short8*)(Al + ((64 * wr + 16 * m + lr) << 5) + (lg << 3));
#pragma unroll
        for (int n = 0; n < 4; ++n)
            bw[n] = *(const short8*)(Bl + ((64 * wc + 16 * n + lr) << 5) + (lg << 3));
#pragma unroll
        for (int m = 0; m < 4; ++m)
#pragma unroll
            for (int n = 0; n < 4; ++n)
                acc[m][n] = __builtin_amdgcn_mfma_f32_16x16x32_bf16(
                    af[m], bw[n], acc[m][n], 0, 0, 0);
        __syncthreads();
    }
}

// ---------------------------------------------------------------------------
// Q/K/V projection. z=0: Q head-major [B,H,S,DK], PRE-SCALED by
// 0.125*log2(e) (fp32 scale, exact temperature; softmax then uses exp2).
// z=1: K head-major, unscaled. z=2: V TRANSPOSED [B,H,DK,S].
// ---------------------------------------------------------------------------
__global__ __launch_bounds__(256) void proj_gemm_kernel(
    const __hip_bfloat16* __restrict__ ins,   // [3][4096*1024]
    const __hip_bfloat16* __restrict__ wts,   // [3][1024*1024]
    const float* __restrict__ b0, const float* __restrict__ b1,
    const float* __restrict__ b2,
    __hip_bfloat16* __restrict__ outs) {
    __shared__ __align__(16) short Al[128 * 32];
    __shared__ __align__(16) short Bl[128 * 32];
    const int z = blockIdx.z;
    const char* Ab = (const char*)(ins + (size_t)z * 4194304)
                     + (size_t)blockIdx.y * 128 * 2048;
    const char* Wb = (const char*)(wts + (size_t)z * 1048576)
                     + (size_t)blockIdx.x * 128 * 2048;
    const float* bias = (z == 0) ? b0 : (z == 1) ? b1 : b2;
    __hip_bfloat16* out = outs + (size_t)z * 4194304;

    f32x4 acc[4][4] = {};
    gemm128_core(Ab, Wb, Al, Bl, acc);

    const int tid = threadIdx.x, lane = tid & 63, wid = tid >> 6;
    const int lr = lane & 15, lg = lane >> 4;
    const int wr = wid >> 1, wc = wid & 1;
    int col0 = (blockIdx.x << 7) + (wc << 6);
    int row0 = (blockIdx.y << 7) + (wr << 6);
    const float scale = (z == 0) ? 0.125f * 1.44269504f : 1.0f;
#pragma unroll
    for (int n = 0; n < 4; ++n) {
        int col = col0 + 16 * n + lr;       // e in [0,1024): h*64+dk
        float bb = bias[col];
        int hh = col >> 6, dk = col & 63;
        if (z == 2) {
#pragma unroll
            for (int m = 0; m < 4; ++m) {
                int row = row0 + 16 * m + 4 * lg;      // b*2048+s (4-aligned)
                int bat = row >> 11, s = row & 2047;
                short4v vv;
#pragma unroll
                for (int r = 0; r < 4; ++r) vv[r] = f2bf(acc[m][n][r] + bb);
                *(short4v*)((short*)out +
                    ((size_t)((bat * 16 + hh) * 64 + dk) << 11) + s) = vv;
            }
        } else {
#pragma unroll
            for (int m = 0; m < 4; ++m)
#pragma unroll
                for (int r = 0; r < 4; ++r) {
                    int row = row0 + 16 * m + 4 * lg + r;
                    int bat = row >> 11, s = row & 2047;
                    out[((size_t)((bat * 16 + hh) * 2048 + s) << 6) + dk] =
                        __float2bfloat16((acc[m][n][r] + bb) * scale);
                }
        }
    }
}

// ---------------------------------------------------------------------------
// Output projection: out = X @ Wo^T + bo, fp32 output.
// ---------------------------------------------------------------------------
__global__ __launch_bounds__(256) void out_gemm_kernel(
    const __hip_bfloat16* __restrict__ X, const __hip_bfloat16* __restrict__ Wo,
    const float* __restrict__ bias, float* __restrict__ out) {
    __shared__ __align__(16) short Al[128 * 32];
    __shared__ __align__(16) short Bl[128 * 32];
    const char* Ab = (const char*)X + (size_t)blockIdx.y * 128 * 2048;
    const char* Wb = (const char*)Wo + (size_t)blockIdx.x * 128 * 2048;
    f32x4 acc[4][4] = {};
    gemm128_core(Ab, Wb, Al, Bl, acc);

    const int tid = threadIdx.x, lane = tid & 63, wid = tid >> 6;
    const int lr = lane & 15, lg = lane >> 4;
    const int wr = wid >> 1, wc = wid & 1;
    int col0 = (blockIdx.x << 7) + (wc << 6);
    int row0 = (blockIdx.y << 7) + (wr << 6);
#pragma unroll
    for (int n = 0; n < 4; ++n) {
        int col = col0 + 16 * n + lr;
        float bb = bias[col];
#pragma unroll
        for (int m = 0; m < 4; ++m)
#pragma unroll
            for (int r = 0; r < 4; ++r) {
                int row = row0 + 16 * m + 4 * lg + r;
                out[((size_t)row << 10) + col] = acc[m][n][r] + bb;
            }
    }
}

// ---------------------------------------------------------------------------
// Flash attention v3, causal. Structure as v2 (pair-balanced blocks, dbuf
// swizzled K/V^T via global_load_lds, counted vmcnt) plus:
//  - mask only the diagonal tile
//  - row-sum l via MFMA against a ones-fragment (no psum shuffle reduce)
//  - rmax reduce via DPP row_ror (VALU, not DS)
//  - defer-max: skip o/l rescale unless row max grows > 10 (log2 domain)
//  - p = exp2(s - m) with Q pre-scaled by 0.125*log2e
//  - s_setprio(1) around MFMA clusters
// ---------------------------------------------------------------------------
#define SWZB(row, cb) ((cb) ^ (((row) & 7) << 4))
#define RESCALE_THR 10.0f

__device__ __forceinline__ void stage_kv(const short* kg, const short* vtg,
                                         short* Kbuf, short* Vbuf, int kv0,
                                         int wid, int lane) {
#pragma unroll
    for (int i = 0; i < 2; ++i) {
        int slot0 = (wid * 2 + i) * 64;
        int slot = slot0 + lane;
        int row = slot >> 3;          // K: kv row / V: dk row
        int cb = (slot & 7) << 4;     // 16B chunk within 128B row
        const char* gk = (const char*)(kg + (size_t)(kv0 + row) * 64)
                         + SWZB(row, cb);
        gload16(gk, (char*)Kbuf + (slot0 << 4));
        const char* gv = (const char*)(vtg + (size_t)row * 2048 + kv0)
                         + SWZB(row, cb);
        gload16(gv, (char*)Vbuf + (slot0 << 4));
    }
}

__global__ __launch_bounds__(256) void attn_kernel(
    const __hip_bfloat16* __restrict__ qb, const __hip_bfloat16* __restrict__ kb,
    const __hip_bfloat16* __restrict__ vtb, __hip_bfloat16* __restrict__ xb) {
    __shared__ __align__(16) short Kl[2][64 * 64];
    __shared__ __align__(16) short Vl[2][64 * 64];   // V^T: [dk][kv]
    __shared__ __align__(16) short Pl[4][16 * 64];
    const int tid = threadIdx.x, lane = tid & 63, wid = tid >> 6;
    const int lr = lane & 15, lg = lane >> 4;
    const int h = blockIdx.y, b = blockIdx.z;
    const size_t hb = (size_t)(b * 16 + h) * (2048 * 64);
    const short* qg = (const short*)qb + hb;
    const short* kg = (const short*)kb + hb;
    const short* vtg = (const short*)vtb + hb;   // [64][2048]
    char* pw = (char*)Pl[wid];
    const short8 ones = {16256, 16256, 16256, 16256,
                         16256, 16256, 16256, 16256};  // bf16 1.0 x8

#pragma unroll 1
    for (int half = 0; half < 2; ++half) {
        const int qt = half ? (31 - (int)blockIdx.x) : (int)blockIdx.x;
        const int q0 = qt << 6;
        const int ntiles = qt + 1;

        // Q fragments straight to registers (row selector = lr)
        short8 qa[2];
        const char* qrow = (const char*)(qg + (size_t)q0 * 64)
                           + (16 * wid + lr) * 128 + (lg << 4);
        qa[0] = *(const short8*)(qrow);
        qa[1] = *(const short8*)(qrow + 64);

        f32x4 o[4] = {};
        f32x4 lacc = {};
        float mrun[4];
#pragma unroll
        for (int r = 0; r < 4; ++r) mrun[r] = -1e30f;
        const int qrow0 = q0 + 16 * wid + 4 * lg;

        stage_kv(kg, vtg, Kl[0], Vl[0], 0, wid, lane);   // prologue
        int cur = 0;
#pragma unroll 1
        for (int t = 0; t < ntiles; ++t) {
            if (t + 1 < ntiles) {
                stage_kv(kg, vtg, Kl[cur ^ 1], Vl[cur ^ 1], (t + 1) << 6,
                         wid, lane);
                asm volatile("s_waitcnt vmcnt(4)" ::: "memory");
            } else {
                asm volatile("s_waitcnt vmcnt(0)" ::: "memory");
            }
            __builtin_amdgcn_s_barrier();   // all waves' slices staged

            const char* Kc = (const char*)Kl[cur];
            const char* Vc = (const char*)Vl[cur];

            // S = Q K^T  (16 q-rows x 64 kv)
            f32x4 sc[4] = {};
            __builtin_amdgcn_s_setprio(1);
#pragma unroll
            for (int kk = 0; kk < 2; ++kk)
#pragma unroll
                for (int n = 0; n < 4; ++n) {
                    int row = 16 * n + lr;
                    short8 kf = *(const short8*)(Kc + row * 128 +
                                    SWZB(row, kk * 64 + (lg << 4)));
                    sc[n] = __builtin_amdgcn_mfma_f32_16x16x32_bf16(
                        qa[kk], kf, sc[n], 0, 0, 0);
                }
            __builtin_amdgcn_s_setprio(0);

            // causal mask: only the diagonal tile needs it
            if (t == qt) {
                const int kv0 = t << 6;
#pragma unroll
                for (int n = 0; n < 4; ++n) {
                    int kvg = kv0 + 16 * n + lr;
#pragma unroll
                    for (int r = 0; r < 4; ++r)
                        if (kvg > qrow0 + r) sc[n][r] = -1e30f;
                }
            }

            // row max: 3 local fmax + 4 DPP row_ror steps (16-lane group)
            float rmax[4];
#pragma unroll
            for (int r = 0; r < 4; ++r) {
                float m = fmaxf(fmaxf(sc[0][r], sc[1][r]),
                                fmaxf(sc[2][r], sc[3][r]));
                m = fmax_ror<0x121>(m);   // ror:1
                m = fmax_ror<0x122>(m);   // ror:2
                m = fmax_ror<0x124>(m);   // ror:4
                m = fmax_ror<0x128>(m);   // ror:8
                rmax[r] = m;
            }

            // defer-max: rescale only when the max grew materially
            bool need = false;
#pragma unroll
            for (int r = 0; r < 4; ++r)
                need |= (rmax[r] > mrun[r] + RESCALE_THR);
            if (need) {
#pragma unroll
                for (int r = 0; r < 4; ++r) {
                    float mnew = fmaxf(mrun[r], rmax[r]);
                    float corr = exp2v(mrun[r] - mnew);
                    mrun[r] = mnew;
                    lacc[r] *= corr;
#pragma unroll
                    for (int n = 0; n < 4; ++n) o[n][r] *= corr;
                }
            }

            // P = exp2(S - m) -> per-wave swizzled LDS tile [16][64]
#pragma unroll
            for (int n = 0; n < 4; ++n)
#pragma unroll
                for (int r = 0; r < 4; ++r) {
                    float p = exp2v(sc[n][r] - mrun[r]);
                    int prow = 4 * lg + r;
                    *(short*)(pw + prow * 128 +
                              SWZB(prow, 32 * n + 2 * lr)) = f2bf(p);
                }

            // O += P @ V ; l += P @ ones  (B-operand = rows of V^T)
            __builtin_amdgcn_s_setprio(1);
#pragma unroll
            for (int kk = 0; kk < 2; ++kk) {
                short8 pa = *(const short8*)(pw + lr * 128 +
                                SWZB(lr, kk * 64 + (lg << 4)));
                lacc = __builtin_amdgcn_mfma_f32_16x16x32_bf16(
                    pa, ones, lacc, 0, 0, 0);
#pragma unroll
                for (int nd = 0; nd < 4; ++nd) {
                    int row = 16 * nd + lr;
                    short8 vf = *(const short8*)(Vc + row * 128 +
                                    SWZB(row, kk * 64 + (lg << 4)));
                    o[nd] = __builtin_amdgcn_mfma_f32_16x16x32_bf16(
                        pa, vf, o[nd], 0, 0, 0);
                }
            }
            __builtin_amdgcn_s_setprio(0);
            __builtin_amdgcn_s_barrier();   // all reads of buf `cur` done
            cur ^= 1;
        }

        // epilogue: x[b][s][h*64+dk] = O / l (bf16)
#pragma unroll
        for (int r = 0; r < 4; ++r) {
            float inv = 1.0f / lacc[r];
            int s = qrow0 + r;
            size_t rowoff = ((size_t)(b * 2048 + s) << 10) + (h << 6);
#pragma unroll
            for (int nd = 0; nd < 4; ++nd)
                xb[rowoff + 16 * nd + lr] = __float2bfloat16(o[nd][r] * inv);
        }
    }
}

// ---------------------------------------------------------------------------
// Workspace layout (bf16 elems):
//   [0,         12582912)  converted query/key/value   (3 x 4194304)
//   [12582912,  16777216)  converted Wq,Wk,Wv,Wo       (4 x 1048576)
//   [16777216,  29360128)  Q(scaled),K head-major; V^T [B,H,DK,S]
//   x-buffer aliases [0, 4194304).
// ---------------------------------------------------------------------------
extern "C" void kernel_launch(void* const* d_in, const int* in_sizes, int n_in,
                              void* d_out, int out_size, void* d_ws, size_t ws_size,
                              hipStream_t stream) {
    const float* query = (const float*)d_in[0];
    const float* key_  = (const float*)d_in[1];
    const float* value = (const float*)d_in[2];
    // d_in[3] = mask: causal tril by construction, handled analytically
    const float* Wq = (const float*)d_in[4];
    const float* bq = (const float*)d_in[5];
    const float* Wk = (const float*)d_in[6];
    const float* bk = (const float*)d_in[7];
    const float* Wv = (const float*)d_in[8];
    const float* bv = (const float*)d_in[9];
    const float* Wo = (const float*)d_in[10];
    const float* bo = (const float*)d_in[11];

    __hip_bfloat16* ws    = (__hip_bfloat16*)d_ws;
    __hip_bfloat16* in_b  = ws;                 // 3 x 4194304
    __hip_bfloat16* w_b   = ws + 12582912;      // 4 x 1048576
    __hip_bfloat16* qkv_b = ws + 16777216;      // 3 x 4194304
    __hip_bfloat16* x_b   = ws;                 // alias converted inputs

    cvt_all_kernel<<<8192, 256, 0, stream>>>(query, key_, value,
                                             Wq, Wk, Wv, Wo, (short*)in_b);
    proj_gemm_kernel<<<dim3(8, 32, 3), 256, 0, stream>>>(in_b, w_b, bq, bk, bv,
                                                         qkv_b);
    attn_kernel<<<dim3(16, 16, 2), 256, 0, stream>>>(qkv_b, qkv_b + 4194304,
                                                     qkv_b + 8388608, x_b);
    out_gemm_kernel<<<dim3(8, 32), 256, 0, stream>>>(x_b, w_b + 3145728, bo,
                                                     (float*)d_out);
}